// Round 10
// baseline (8490.363 us; speedup 1.0000x reference)
//
#include <hip/hip_runtime.h>
#include <hip/hip_fp16.h>
#include <stdint.h>

// Reservoir recurrence, persistent-wave dataflow, round 10.
//   s_{t+1} = tanh(u_t + 0.9 * W_res @ s_t) / sqrt(2048)
// One-hop fused exchange: 8B unit = (2 x f16 state | u32 step tag), single
// relaxed agent-scope 64-bit atomic store; consumers validate by tag.
// vs R9: (1) weight prefetch is FORCED resident -- keep-alive asm uses the
// 16 ds_read_b128 results before the poll (lgkmcnt drains there; values stay
// in VGPRs across the poll; R9's VGPR_Count=88 proved the compiler was
// rematerializing). (2) two-stream staggered poll halves the detection
// period (two independent in-flight tag loads checked alternately; stale
// payloads are safe because the tag validates them).

#define RES     2048
#define ROWSPW  4                    // rows per wave
#define WPB     8                    // waves per block
#define ROWSPB  (ROWSPW * WPB)       // 32 rows per block
#define NBLK    (RES / ROWSPB)       // 64 blocks
#define NUNITS  (RES / 2)            // 1024 8-byte exchange units
#define UPB     (ROWSPB / 2)         // 16 units published per block
#define UPW     (NUNITS / WPB / 64)  // 2 unit-loads per lane per poll round
#define KPL     (RES / 2 / 64)       // 16 u32 weight words per lane per row
#define CHK     (KPL / 4)            // 4 b128 chunks per lane per row

typedef _Float16 half2v __attribute__((ext_vector_type(2)));

union H2U { half2v h; uint32_t u; };

__device__ __forceinline__ uint32_t pack_h2(float a, float b) {
  H2U c; c.h.x = (_Float16)a; c.h.y = (_Float16)b; return c.u;
}
__device__ __forceinline__ half2v u_to_h2(uint32_t u) { H2U c; c.u = u; return c.h; }

__device__ __forceinline__ float dot2acc(uint32_t wu, uint32_t su, float acc) {
#if __has_builtin(__builtin_amdgcn_fdot2)
  return __builtin_amdgcn_fdot2(u_to_h2(wu), u_to_h2(su), acc, false);
#else
  half2v w = u_to_h2(wu), s = u_to_h2(su);
  acc = fmaf((float)w.x, (float)s.x, acc);
  return fmaf((float)w.y, (float)s.y, acc);
#endif
}

__device__ __forceinline__ float fast_tanh(float x) {
  // tanh(x) = 1 - 2/(e^{2x}+1); saturates to exactly +-1 on over/underflow.
  float e = __expf(2.0f * x);
  return 1.0f - 2.0f / (e + 1.0f);
}

__device__ __forceinline__ float merge_red(float lo, float hi, int mask, int lane) {
  // Lanes with (lane&mask)==0 end up carrying lo's pair-sum, others hi's.
  float sel  = (lane & mask) ? lo : hi;
  float keep = (lane & mask) ? hi : lo;
  return keep + __shfl_xor(sel, mask);
}

__global__ void reservoir_init(const float* __restrict__ s0,
                               float* __restrict__ out,
                               uint64_t* __restrict__ buf0,
                               uint64_t* __restrict__ buf1,
                               int res) {
  int i = blockIdx.x * blockDim.x + threadIdx.x;
  if (i < res) out[i] = s0[i];            // output row 0 = initial_state (f32)
  if (i < res / 2) {
    uint32_t a = (uint32_t)__half_as_ushort(__float2half_rn(s0[2 * i]));
    uint32_t b = (uint32_t)__half_as_ushort(__float2half_rn(s0[2 * i + 1]));
    buf0[i] = (uint64_t)(a | (b << 16));  // payload low, tag 0 high
    buf1[i] = 0xFFFFFFFF00000000ull;      // poison tag (never matches 0..4096)
  }
}

__global__ void __launch_bounds__(512, 1)
reservoir_main(const float* __restrict__ in,     // (seq, isz) f32
               const float* __restrict__ W_in,   // (RES, isz) f32
               const float* __restrict__ W_res,  // (RES, RES) f32
               float* __restrict__ out,          // (seq+1, RES) f32
               uint64_t* __restrict__ buf0,
               uint64_t* __restrict__ buf1,
               int seq, int isz) {
  const int lane = threadIdx.x & 63;
  const int q    = threadIdx.x >> 6;              // wave index in block, 0..7
  const int W    = blockIdx.x * WPB + q;          // global wave id, 0..511
  const int r0   = W * ROWSPW;                    // first owned state row

  // LDS: 128 KB weights + 8 KB pay + publish gather = ~139 KB (1 block/CU).
  __shared__ uint32_t wlds[ROWSPB * (RES / 2)];   // [32 rows][1024 half2]
  __shared__ uint32_t pay[2][NUNITS];             // staged payloads per parity
  __shared__ uint32_t ous[UPB];                   // block publish gather

  // ---- one-time: stage this wave's 4 rows into LDS as f16 pairs, x0.9.
#pragma unroll
  for (int r = 0; r < ROWSPW; ++r) {
    const int lr = q * ROWSPW + r;                // local row in block
    const float* wr = W_res + (size_t)(r0 + r) * RES;
    uint32_t* wl = &wlds[lr * (RES / 2)];
#pragma unroll
    for (int jj = 0; jj < KPL; ++jj) {
      int k = lane + 64 * jj;
      float2 p2 = *(const float2*)(wr + 2 * k);
      wl[k] = pack_h2(0.9f * p2.x, 0.9f * p2.y);
    }
  }
  // (no barrier needed: each wave reads only the rows it wrote)

  // W_in slice: lane l holds input columns 2l, 2l+1 for its 4 rows (f32).
  float win[ROWSPW][2];
#pragma unroll
  for (int r = 0; r < ROWSPW; ++r) {
    float2 p2 = *(const float2*)(W_in + (size_t)(r0 + r) * isz + 2 * lane);
    win[r][0] = p2.x;
    win[r][1] = p2.y;
  }

  const float inv_sqrt_n = 0.022097086912079612f;  // 1/sqrt(2048)

  // prefetch input row 0 (lane l -> cols 2l, 2l+1)
  float2 xin = *(const float2*)(in + 2 * lane);

  const int ubase = q * (NUNITS / WPB) + lane;     // this wave's poll slice

  for (int t = 0; t < seq; ++t) {
    const int p = t & 1;
    const uint64_t* src = p ? buf1 : buf0;  // holds s_t (tag == t)
    uint64_t* dst       = p ? buf0 : buf1;  // will hold s_{t+1}
    const uint32_t want = (uint32_t)t;
    const uint64_t* sp  = src + ubase;

    // ---- weight reads for this step (state-independent): 16 x ds_read_b128,
    // then a keep-alive USE of every word -> lgkmcnt drains HERE (before the
    // poll) and the 64 values stay live in VGPRs across the poll. For waves
    // that would wait anyway this is free; it removes the post-barrier
    // weight stream from the critical path.
    uint4 wv[ROWSPW][CHK];
#pragma unroll
    for (int r = 0; r < ROWSPW; ++r)
#pragma unroll
      for (int m = 0; m < CHK; ++m)
        wv[r][m] = *reinterpret_cast<const uint4*>(
            &wlds[(q * ROWSPW + r) * (RES / 2) + 4 * (lane + 64 * m)]);
#pragma unroll
    for (int r = 0; r < ROWSPW; ++r)
      asm volatile("" ::
        "v"(wv[r][0].x), "v"(wv[r][0].y), "v"(wv[r][0].z), "v"(wv[r][0].w),
        "v"(wv[r][1].x), "v"(wv[r][1].y), "v"(wv[r][1].z), "v"(wv[r][1].w),
        "v"(wv[r][2].x), "v"(wv[r][2].y), "v"(wv[r][2].z), "v"(wv[r][2].w),
        "v"(wv[r][3].x), "v"(wv[r][3].y), "v"(wv[r][3].z), "v"(wv[r][3].w));

    // ---- two-stream staggered poll: two independent in-flight copies of
    // the 2 tag loads, checked alternately -> detection period halves.
    uint32_t dw[UPW];
    {
      uint64_t vA[UPW], vB[UPW];
#pragma unroll
      for (int k = 0; k < UPW; ++k)
        vA[k] = __hip_atomic_load(sp + 64 * k, __ATOMIC_RELAXED,
                                  __HIP_MEMORY_SCOPE_AGENT);
      for (;;) {
#pragma unroll
        for (int k = 0; k < UPW; ++k)
          vB[k] = __hip_atomic_load(sp + 64 * k, __ATOMIC_RELAXED,
                                    __HIP_MEMORY_SCOPE_AGENT);
        bool ok = true;
#pragma unroll
        for (int k = 0; k < UPW; ++k)
          ok &= ((uint32_t)(vA[k] >> 32) == want);
        if (__all(ok)) {
#pragma unroll
          for (int k = 0; k < UPW; ++k) dw[k] = (uint32_t)vA[k];
          break;
        }
#pragma unroll
        for (int k = 0; k < UPW; ++k)
          vA[k] = __hip_atomic_load(sp + 64 * k, __ATOMIC_RELAXED,
                                    __HIP_MEMORY_SCOPE_AGENT);
        ok = true;
#pragma unroll
        for (int k = 0; k < UPW; ++k)
          ok &= ((uint32_t)(vB[k] >> 32) == want);
        if (__all(ok)) {
#pragma unroll
          for (int k = 0; k < UPW; ++k) dw[k] = (uint32_t)vB[k];
          break;
        }
      }
    }

    // ---- stage validated payloads in LDS; barrier publishes them block-wide
#pragma unroll
    for (int k = 0; k < UPW; ++k)
      pay[p][ubase + 64 * k] = dw[k];
    __syncthreads();

    // ---- accumulators start with the input projection (INPUT_SCALE = 1)
    float acc[ROWSPW];
#pragma unroll
    for (int r = 0; r < ROWSPW; ++r)
      acc[r] = fmaf(xin.y, win[r][1], xin.x * win[r][0]);

    // ---- matvec: per chunk m, one uint4 of state (8 cols) shared across the
    // wave's 4 rows; weights already resident in VGPRs.
#pragma unroll
    for (int m = 0; m < CHK; ++m) {
      const int ki = 4 * (lane + 64 * m);
      uint4 sv = *reinterpret_cast<const uint4*>(&pay[p][ki]);
#pragma unroll
      for (int r = 0; r < ROWSPW; ++r) {
        acc[r] = dot2acc(wv[r][m].x, sv.x, acc[r]);
        acc[r] = dot2acc(wv[r][m].y, sv.y, acc[r]);
        acc[r] = dot2acc(wv[r][m].z, sv.z, acc[r]);
        acc[r] = dot2acc(wv[r][m].w, sv.w, acc[r]);
      }
    }

    // ---- merged butterfly: 7 shfls; lane l ends holding row r0 + (l & 3)
    float m0 = merge_red(acc[0], acc[1], 1, lane);
    float m1 = merge_red(acc[2], acc[3], 1, lane);
    float qq = merge_red(m0, m1, 2, lane);
    qq += __shfl_xor(qq, 4);
    qq += __shfl_xor(qq, 8);
    qq += __shfl_xor(qq, 16);
    qq += __shfl_xor(qq, 32);

    float o = fast_tanh(qq) * inv_sqrt_n;

    // ---- gather the block's 32 rows (16 packed u32) into LDS
    uint32_t hu = (uint32_t)__half_as_ushort(__float2half_rn(o));
    uint32_t up = (uint32_t)__shfl_xor((int)hu, 1);     // partner row's half
    uint32_t word = (hu & 0xffffu) | (up << 16);        // valid on even lanes
    if (lane == 0 || lane == 2)
      ous[2 * q + (lane >> 1)] = word;

    // f32 output row (off the critical path, before the barrier)
    if (lane < ROWSPW)
      out[(size_t)(t + 1) * RES + r0 + lane] = o;

    __syncthreads();

    // ---- publish: wave 0 stores the block's 16 tagged units (128B
    // coalesced; 64 MALL write transactions grid-wide). No WAR on `ous`:
    // nobody passes the next poll until this store is visible, and the
    // store reads ous first.
    if (q == 0 && lane < UPB) {
      uint64_t val = ((uint64_t)(uint32_t)(t + 1) << 32) | (uint64_t)ous[lane];
      __hip_atomic_store(dst + UPB * blockIdx.x + lane, val, __ATOMIC_RELAXED,
                         __HIP_MEMORY_SCOPE_AGENT);
    }

    // prefetch next input row
    int tn = (t + 1 < seq) ? (t + 1) : t;
    xin = *(const float2*)(in + (size_t)tn * isz + 2 * lane);
  }
}

extern "C" void kernel_launch(void* const* d_in, const int* in_sizes, int n_in,
                              void* d_out, int out_size, void* d_ws, size_t ws_size,
                              hipStream_t stream) {
  const float* input = (const float*)d_in[0];   // (seq, isz)
  const float* s0    = (const float*)d_in[1];   // (res,)
  const float* W_in  = (const float*)d_in[2];   // (res, isz)
  const float* W_res = (const float*)d_in[3];   // (res, res)
  float* out = (float*)d_out;

  const int res = in_sizes[1];             // 2048
  const int isz = in_sizes[2] / res;       // 128
  const int seq = in_sizes[0] / isz;       // 4096

  uint64_t* buf0 = (uint64_t*)d_ws;        // res/2 units
  uint64_t* buf1 = buf0 + res / 2;         // res/2 units (16 KB total)

  reservoir_init<<<(res + 255) / 256, 256, 0, stream>>>(s0, out, buf0, buf1, res);
  reservoir_main<<<NBLK, WPB * 64, 0, stream>>>(input, W_in, W_res, out,
                                                buf0, buf1, seq, isz);
}

// Round 11
// 6556.602 us; speedup vs baseline: 1.2949x; 1.2949x over previous
//
#include <hip/hip_runtime.h>
#include <hip/hip_fp16.h>
#include <stdint.h>

// Reservoir recurrence, persistent-wave dataflow, round 11.
//   s_{t+1} = tanh(u_t + 0.9 * W_res @ s_t) / sqrt(2048)
// One-hop fused exchange: 8B unit = (2 x f16 state | u32 step tag), single
// relaxed agent-scope 64-bit atomic store; consumers validate by tag.
// vs R9/R10: weights live in VGPRs for the WHOLE kernel. Each packed f16-pair
// word is laundered through an `asm volatile` OUTPUT once before the t-loop:
// volatile-asm-produced values cannot be rematerialized, so regalloc must
// keep all 64 words resident (cap 256 regs/wave at launch_bounds(512,1); R7's
// spill was the (512,2)=128 cap, R9/R10's failure was remat, not capacity).
// This deletes the 128KB LDS weight array AND the per-step ds_read stream.
// R10's scalarized keep-alive (bank-conflict explosion) is reverted.

#define RES     2048
#define ROWSPW  4                    // rows per wave
#define WPB     8                    // waves per block
#define ROWSPB  (ROWSPW * WPB)       // 32 rows per block
#define NBLK    (RES / ROWSPB)       // 64 blocks
#define NUNITS  (RES / 2)            // 1024 8-byte exchange units
#define UPB     (ROWSPB / 2)         // 16 units published per block
#define UPW     (NUNITS / WPB / 64)  // 2 unit-loads per lane per poll round
#define KPL     (RES / 2 / 64)       // 16 u32 weight words per lane per row
#define CHK     (KPL / 4)            // 4 state chunks (uint4) per lane

typedef _Float16 half2v __attribute__((ext_vector_type(2)));

union H2U { half2v h; uint32_t u; };

__device__ __forceinline__ uint32_t pack_h2(float a, float b) {
  H2U c; c.h.x = (_Float16)a; c.h.y = (_Float16)b; return c.u;
}
__device__ __forceinline__ half2v u_to_h2(uint32_t u) { H2U c; c.u = u; return c.h; }

__device__ __forceinline__ float dot2acc(uint32_t wu, uint32_t su, float acc) {
#if __has_builtin(__builtin_amdgcn_fdot2)
  return __builtin_amdgcn_fdot2(u_to_h2(wu), u_to_h2(su), acc, false);
#else
  half2v w = u_to_h2(wu), s = u_to_h2(su);
  acc = fmaf((float)w.x, (float)s.x, acc);
  return fmaf((float)w.y, (float)s.y, acc);
#endif
}

__device__ __forceinline__ float fast_tanh(float x) {
  // tanh(x) = 1 - 2/(e^{2x}+1); saturates to exactly +-1 on over/underflow.
  float e = __expf(2.0f * x);
  return 1.0f - 2.0f / (e + 1.0f);
}

__device__ __forceinline__ float merge_red(float lo, float hi, int mask, int lane) {
  // Lanes with (lane&mask)==0 end up carrying lo's pair-sum, others hi's.
  float sel  = (lane & mask) ? lo : hi;
  float keep = (lane & mask) ? hi : lo;
  return keep + __shfl_xor(sel, mask);
}

__global__ void reservoir_init(const float* __restrict__ s0,
                               float* __restrict__ out,
                               uint64_t* __restrict__ buf0,
                               uint64_t* __restrict__ buf1,
                               int res) {
  int i = blockIdx.x * blockDim.x + threadIdx.x;
  if (i < res) out[i] = s0[i];            // output row 0 = initial_state (f32)
  if (i < res / 2) {
    uint32_t a = (uint32_t)__half_as_ushort(__float2half_rn(s0[2 * i]));
    uint32_t b = (uint32_t)__half_as_ushort(__float2half_rn(s0[2 * i + 1]));
    buf0[i] = (uint64_t)(a | (b << 16));  // payload low, tag 0 high
    buf1[i] = 0xFFFFFFFF00000000ull;      // poison tag (never matches 0..4096)
  }
}

__global__ void __launch_bounds__(512, 1)
reservoir_main(const float* __restrict__ in,     // (seq, isz) f32
               const float* __restrict__ W_in,   // (RES, isz) f32
               const float* __restrict__ W_res,  // (RES, RES) f32
               float* __restrict__ out,          // (seq+1, RES) f32
               uint64_t* __restrict__ buf0,
               uint64_t* __restrict__ buf1,
               int seq, int isz) {
  const int lane = threadIdx.x & 63;
  const int q    = threadIdx.x >> 6;              // wave index in block, 0..7
  const int W    = blockIdx.x * WPB + q;          // global wave id, 0..511
  const int r0   = W * ROWSPW;                    // first owned state row

  __shared__ uint32_t pay[2][NUNITS];             // staged payloads per parity
  __shared__ uint32_t ous[UPB];                   // block publish gather

  // ---- one-time: this wave's 4 rows of W_res into VGPRs as f16 pairs, x0.9.
  // Weight word j = 4m+c (m<4, c<4) holds cols {2k, 2k+1} for k = 4*(lane+
  // 64m)+c -- exactly matching the step-time state chunk uint4 at
  // pay[4*(lane+64m)]. Loaded as two coalesced float4 per (row, m).
  // Each packed word is laundered through a volatile-asm OUTPUT: the value
  // becomes non-rematerializable, forcing whole-kernel VGPR residency.
  uint32_t w[ROWSPW][KPL];
#pragma unroll
  for (int r = 0; r < ROWSPW; ++r) {
    const float* wr = W_res + (size_t)(r0 + r) * RES;
#pragma unroll
    for (int m = 0; m < CHK; ++m) {
      const int col0 = 8 * (lane + 64 * m);       // first of 8 f32 cols
      float4 a = *(const float4*)(wr + col0);
      float4 b = *(const float4*)(wr + col0 + 4);
      uint32_t t0 = pack_h2(0.9f * a.x, 0.9f * a.y);
      uint32_t t1 = pack_h2(0.9f * a.z, 0.9f * a.w);
      uint32_t t2 = pack_h2(0.9f * b.x, 0.9f * b.y);
      uint32_t t3 = pack_h2(0.9f * b.z, 0.9f * b.w);
      asm volatile("" : "=v"(w[r][4 * m + 0]) : "0"(t0));
      asm volatile("" : "=v"(w[r][4 * m + 1]) : "0"(t1));
      asm volatile("" : "=v"(w[r][4 * m + 2]) : "0"(t2));
      asm volatile("" : "=v"(w[r][4 * m + 3]) : "0"(t3));
    }
  }

  // W_in slice: lane l holds input columns 2l, 2l+1 for its 4 rows (f32).
  float win[ROWSPW][2];
#pragma unroll
  for (int r = 0; r < ROWSPW; ++r) {
    float2 p2 = *(const float2*)(W_in + (size_t)(r0 + r) * isz + 2 * lane);
    win[r][0] = p2.x;
    win[r][1] = p2.y;
  }

  const float inv_sqrt_n = 0.022097086912079612f;  // 1/sqrt(2048)

  // prefetch input row 0 (lane l -> cols 2l, 2l+1)
  float2 xin = *(const float2*)(in + 2 * lane);

  const int ubase = q * (NUNITS / WPB) + lane;     // this wave's poll slice

  for (int t = 0; t < seq; ++t) {
    const int p = t & 1;
    const uint64_t* src = p ? buf1 : buf0;  // holds s_t (tag == t)
    uint64_t* dst       = p ? buf0 : buf1;  // will hold s_{t+1}
    const uint32_t want = (uint32_t)t;

    // ---- poll this wave's slice: 2 batched 8B loads, single wait (R9 form)
    uint32_t dw[UPW];
    for (;;) {
      uint64_t v[UPW];
#pragma unroll
      for (int k = 0; k < UPW; ++k)
        v[k] = __hip_atomic_load(src + ubase + 64 * k, __ATOMIC_RELAXED,
                                 __HIP_MEMORY_SCOPE_AGENT);
      bool ok = true;
#pragma unroll
      for (int k = 0; k < UPW; ++k)
        ok &= ((uint32_t)(v[k] >> 32) == want);
      if (__all(ok)) {
#pragma unroll
        for (int k = 0; k < UPW; ++k) dw[k] = (uint32_t)v[k];
        break;
      }
    }

    // ---- stage validated payloads in LDS; barrier publishes them block-wide
#pragma unroll
    for (int k = 0; k < UPW; ++k)
      pay[p][ubase + 64 * k] = dw[k];
    __syncthreads();

    // ---- accumulators start with the input projection (INPUT_SCALE = 1)
    float acc[ROWSPW];
#pragma unroll
    for (int r = 0; r < ROWSPW; ++r)
      acc[r] = fmaf(xin.y, win[r][1], xin.x * win[r][0]);

    // ---- matvec: per chunk m, one uint4 of state (8 cols, ds_read_b128,
    // lane-contiguous = conflict-free) shared across the wave's 4 rows;
    // weights come straight from resident VGPRs.
#pragma unroll
    for (int m = 0; m < CHK; ++m) {
      const int ki = 4 * (lane + 64 * m);
      uint4 sv = *reinterpret_cast<const uint4*>(&pay[p][ki]);
#pragma unroll
      for (int r = 0; r < ROWSPW; ++r) {
        acc[r] = dot2acc(w[r][4 * m + 0], sv.x, acc[r]);
        acc[r] = dot2acc(w[r][4 * m + 1], sv.y, acc[r]);
        acc[r] = dot2acc(w[r][4 * m + 2], sv.z, acc[r]);
        acc[r] = dot2acc(w[r][4 * m + 3], sv.w, acc[r]);
      }
    }

    // ---- merged butterfly: 7 shfls; lane l ends holding row r0 + (l & 3)
    float m0 = merge_red(acc[0], acc[1], 1, lane);
    float m1 = merge_red(acc[2], acc[3], 1, lane);
    float qq = merge_red(m0, m1, 2, lane);
    qq += __shfl_xor(qq, 4);
    qq += __shfl_xor(qq, 8);
    qq += __shfl_xor(qq, 16);
    qq += __shfl_xor(qq, 32);

    float o = fast_tanh(qq) * inv_sqrt_n;

    // ---- gather the block's 32 rows (16 packed u32) into LDS
    uint32_t hu = (uint32_t)__half_as_ushort(__float2half_rn(o));
    uint32_t up = (uint32_t)__shfl_xor((int)hu, 1);     // partner row's half
    uint32_t word = (hu & 0xffffu) | (up << 16);        // valid on even lanes
    if (lane == 0 || lane == 2)
      ous[2 * q + (lane >> 1)] = word;

    // f32 output row (off the critical path, before the barrier)
    if (lane < ROWSPW)
      out[(size_t)(t + 1) * RES + r0 + lane] = o;

    __syncthreads();

    // ---- publish: wave 0 stores the block's 16 tagged units (128B
    // coalesced; 64 MALL write transactions grid-wide). No WAR on `ous`:
    // nobody passes the next poll until this store is visible, and the
    // store reads ous first.
    if (q == 0 && lane < UPB) {
      uint64_t val = ((uint64_t)(uint32_t)(t + 1) << 32) | (uint64_t)ous[lane];
      __hip_atomic_store(dst + UPB * blockIdx.x + lane, val, __ATOMIC_RELAXED,
                         __HIP_MEMORY_SCOPE_AGENT);
    }

    // prefetch next input row
    int tn = (t + 1 < seq) ? (t + 1) : t;
    xin = *(const float2*)(in + (size_t)tn * isz + 2 * lane);
  }
}

extern "C" void kernel_launch(void* const* d_in, const int* in_sizes, int n_in,
                              void* d_out, int out_size, void* d_ws, size_t ws_size,
                              hipStream_t stream) {
  const float* input = (const float*)d_in[0];   // (seq, isz)
  const float* s0    = (const float*)d_in[1];   // (res,)
  const float* W_in  = (const float*)d_in[2];   // (res, isz)
  const float* W_res = (const float*)d_in[3];   // (res, res)
  float* out = (float*)d_out;

  const int res = in_sizes[1];             // 2048
  const int isz = in_sizes[2] / res;       // 128
  const int seq = in_sizes[0] / isz;       // 4096

  uint64_t* buf0 = (uint64_t*)d_ws;        // res/2 units
  uint64_t* buf1 = buf0 + res / 2;         // res/2 units (16 KB total)

  reservoir_init<<<(res + 255) / 256, 256, 0, stream>>>(s0, out, buf0, buf1, res);
  reservoir_main<<<NBLK, WPB * 64, 0, stream>>>(input, W_in, W_res, out,
                                                buf0, buf1, seq, isz);
}